// Round 10
// baseline (451.463 us; speedup 1.0000x reference)
//
#include <hip/hip_runtime.h>
#include <hip/hip_bf16.h>
#include <cstddef>

// Shapes (fixed): B=4, H=W=64, C=256, G=8, K=9.
constexpr int HWP = 64 * 64;
constexpr int CCH = 256;
constexpr int OMC = 216;   // G*3*K
constexpr int KDC = 2304;  // 9*256

typedef __attribute__((ext_vector_type(8))) short bf16x8;
typedef __attribute__((ext_vector_type(4))) float f32x4;

__device__ inline unsigned short f2bf(float x) {
  __hip_bfloat16 h = __float2bfloat16(x);
  return *reinterpret_cast<unsigned short*>(&h);
}
__device__ inline float bf2f(unsigned short u) {
  unsigned int v = ((unsigned int)u) << 16;
  return __uint_as_float(v);
}
// unpack a uint holding two bf16: lo -> a, hi -> b
__device__ inline void bfpair(unsigned int u, float& a, float& b) {
  a = __uint_as_float(u << 16);
  b = __uint_as_float(u & 0xffff0000u);
}

// ---------------------------------------------------------------------------
// prep: w_offT[512 n][512 k] ; w_omT[9][256 n(pad)][512 c] ; w_selT[256][256] ;
//       w_dcnT[9][256 f][256 c]   (all bf16)
// ---------------------------------------------------------------------------
__global__ __launch_bounds__(256) void prep_weights(
    const float* __restrict__ w_off, const float* __restrict__ w_om,
    const float* __restrict__ w_sel, const float* __restrict__ w_dcn,
    unsigned short* __restrict__ w_offT, unsigned short* __restrict__ w_omT,
    unsigned short* __restrict__ w_selT, unsigned short* __restrict__ w_dcnT) {
  int i = blockIdx.x * 256 + threadIdx.x;
  if (i < 512 * 512) {
    int n = i >> 9, k = i & 511;
    w_offT[i] = f2bf(w_off[k * 512 + n]);
  }
  if (i < 9 * 256 * 512) {
    int c = i & 511;
    int r = i >> 9;            // tap*256 + n
    int tap = r >> 8;
    int n = r & 255;
    w_omT[i] = f2bf(n < OMC ? w_om[((size_t)tap * 512 + c) * OMC + n] : 0.f);
  }
  if (i < 256 * 256) {
    int n = i >> 8, k = i & 255;
    w_selT[i] = f2bf(w_sel[k * 256 + n]);
  }
  if (i < 9 * 256 * 256) {
    int tap = i >> 16, f = (i >> 8) & 255, c = i & 255;
    w_dcnT[i] = f2bf(w_dcn[((size_t)tap * 256 + c) * 256 + f]);
  }
}

// ---------------------------------------------------------------------------
// Stage 1a/1b: pooled mean (parallel) + attn matvec + sigmoid
// ---------------------------------------------------------------------------
__global__ __launch_bounds__(256) void pool_partial(
    const float* __restrict__ fine, float* __restrict__ partial) {
  int r = blockIdx.x;  // 0..63
  int b = blockIdx.y;  // 0..3
  int t = threadIdx.x;
  const float* src = fine + ((size_t)b * 4096 + r * 64) * 256 + t;
  float s = 0.f;
#pragma unroll 8
  for (int p = 0; p < 64; ++p) s += src[(size_t)p * 256];
  partial[((size_t)b * 64 + r) * 256 + t] = s;
}

__global__ __launch_bounds__(256) void pool_finish(
    const float* __restrict__ partial, const float* __restrict__ w_att,
    float* __restrict__ scale) {
  __shared__ float pl[256];
  int b = blockIdx.x;
  int t = threadIdx.x;
  const float* pp = partial + (size_t)b * 64 * 256 + t;
  float s = 0.f;
#pragma unroll 8
  for (int r = 0; r < 64; ++r) s += pp[(size_t)r * 256];
  pl[t] = s * (1.0f / 4096.0f);
  __syncthreads();
  float acc = 0.f;
  for (int ci = 0; ci < 256; ++ci) acc += pl[ci] * w_att[ci * 256 + t];
  scale[b * 256 + t] = 1.0f + 1.0f / (1.0f + expf(-acc));
}

// ---------------------------------------------------------------------------
// Stage 2: bilinear upsample 32->64 -> upbf (bf16, for dcn sampling) and
//          bf16 2*up into alignA cols 256..511
// ---------------------------------------------------------------------------
__global__ __launch_bounds__(256) void upsample_kernel(
    const float* __restrict__ coarse, unsigned short* __restrict__ upbf,
    unsigned short* __restrict__ alignA) {
  int m = blockIdx.x;  // b*4096 + h*64 + w
  int c = threadIdx.x;
  int b = m >> 12, h = (m >> 6) & 63, w = m & 63;
  float cy = fminf(fmaxf(h * 0.5f - 0.25f, 0.f), 31.f);
  float cx = fminf(fmaxf(w * 0.5f - 0.25f, 0.f), 31.f);
  int y0 = (int)cy, x0 = (int)cx;
  float fy = cy - y0, fx = cx - x0;
  int y1 = min(y0 + 1, 31), x1 = min(x0 + 1, 31);
  const float* base = coarse + (size_t)b * 32 * 32 * CCH;
  float v00 = base[(y0 * 32 + x0) * CCH + c];
  float v01 = base[(y0 * 32 + x1) * CCH + c];
  float v10 = base[(y1 * 32 + x0) * CCH + c];
  float v11 = base[(y1 * 32 + x1) * CCH + c];
  float top = v00 + (v01 - v00) * fx;
  float bot = v10 + (v11 - v10) * fx;
  float v = top + (bot - top) * fy;
  upbf[(size_t)m * CCH + c] = f2bf(v);
  alignA[(size_t)m * 512 + 256 + c] = f2bf(2.f * v);
}

// ---------------------------------------------------------------------------
// Stage 3 (MFMA): fine_cal = (fine*scale) @ w_sel -> fp32 finecal (residual)
//                 + bf16 copy into alignA cols 0..255.  Tile 128x64, BK=64.
// VGPR-prefetch pipeline: load tile k+1 into regs before MFMA(k); single LDS
// buffer; 2 barriers/iter. Keeps 27.6KB LDS -> high occupancy + hidden latency.
// ---------------------------------------------------------------------------
__global__ __launch_bounds__(256) void gemm_finecal_mfma(
    const float* __restrict__ fine, const float* __restrict__ scale,
    const unsigned short* __restrict__ w_selT,   // [256 n][256 k]
    float* __restrict__ finecal, unsigned short* __restrict__ alignA) {
  __shared__ unsigned short As[128][72];
  __shared__ unsigned short Bs[64][72];
  __shared__ float sc[256];
  int n0 = blockIdx.x * 64;
  int m0 = blockIdx.y * 128;
  int t = threadIdx.x;
  int wid = t >> 6, lane = t & 63;
  int lrow = lane & 15, lq = lane >> 4;
  int bb = m0 >> 12;  // 128 | 4096: no batch straddle
  sc[t] = scale[bb * 256 + t];
  f32x4 acc[2][4];
#pragma unroll
  for (int i = 0; i < 2; ++i)
#pragma unroll
    for (int j = 0; j < 4; ++j) acc[i][j] = (f32x4){0.f, 0.f, 0.f, 0.f};

  int arow = t >> 3, ack = t & 7;  // A rows arow+{0,32,64,96}; B rows arow,+32
  float4 paf[4][2];
  uint4 pb[2];
  auto loadA = [&](int k0) {
#pragma unroll
    for (int i = 0; i < 4; ++i) {
      const float* fp = &fine[(size_t)(m0 + arow + i * 32) * 256 + k0 + ack * 8];
      paf[i][0] = *(const float4*)fp;
      paf[i][1] = *(const float4*)(fp + 4);
    }
  };
  auto loadB = [&](int k0) {
#pragma unroll
    for (int i = 0; i < 2; ++i)
      pb[i] = *(const uint4*)&w_selT[(size_t)(n0 + arow + i * 32) * 256 + k0 + ack * 8];
  };
  auto storeT = [&](int k0) {
    int kb = k0 + ack * 8;
    float s0 = sc[kb], s1 = sc[kb + 1], s2 = sc[kb + 2], s3 = sc[kb + 3];
    float s4 = sc[kb + 4], s5 = sc[kb + 5], s6 = sc[kb + 6], s7 = sc[kb + 7];
#pragma unroll
    for (int i = 0; i < 4; ++i) {
      ushort4 u0 = make_ushort4(f2bf(paf[i][0].x * s0), f2bf(paf[i][0].y * s1),
                                f2bf(paf[i][0].z * s2), f2bf(paf[i][0].w * s3));
      ushort4 u1 = make_ushort4(f2bf(paf[i][1].x * s4), f2bf(paf[i][1].y * s5),
                                f2bf(paf[i][1].z * s6), f2bf(paf[i][1].w * s7));
      *(ushort4*)&As[arow + i * 32][ack * 8] = u0;
      *(ushort4*)&As[arow + i * 32][ack * 8 + 4] = u1;
    }
#pragma unroll
    for (int i = 0; i < 2; ++i)
      *(uint4*)&Bs[arow + i * 32][ack * 8] = pb[i];
  };

  loadA(0);
  loadB(0);
  __syncthreads();  // sc visible
  storeT(0);
  __syncthreads();
  for (int kb = 0; kb < 4; ++kb) {
    bool has_next = (kb + 1) < 4;
    if (has_next) { loadA((kb + 1) * 64); loadB((kb + 1) * 64); }
#pragma unroll
    for (int kk = 0; kk < 2; ++kk) {
      bf16x8 a[2], b[4];
#pragma unroll
      for (int mt = 0; mt < 2; ++mt)
        a[mt] = *(const bf16x8*)&As[wid * 32 + mt * 16 + lrow][kk * 32 + lq * 8];
#pragma unroll
      for (int nt = 0; nt < 4; ++nt)
        b[nt] = *(const bf16x8*)&Bs[nt * 16 + lrow][kk * 32 + lq * 8];
#pragma unroll
      for (int mt = 0; mt < 2; ++mt)
#pragma unroll
        for (int nt = 0; nt < 4; ++nt)
          acc[mt][nt] = __builtin_amdgcn_mfma_f32_16x16x32_bf16(
              a[mt], b[nt], acc[mt][nt], 0, 0, 0);
    }
    if (has_next) {
      __syncthreads();           // readers of current tile done
      storeT((kb + 1) * 64);     // vmcnt waits here, after MFMA cover
      __syncthreads();
    }
  }
#pragma unroll
  for (int mt = 0; mt < 2; ++mt)
#pragma unroll
    for (int nt = 0; nt < 4; ++nt)
#pragma unroll
      for (int r = 0; r < 4; ++r) {
        int m = m0 + wid * 32 + mt * 16 + lq * 4 + r;
        int n = n0 + nt * 16 + lrow;
        finecal[(size_t)m * 256 + n] = acc[mt][nt][r];
        alignA[(size_t)m * 512 + n] = f2bf(acc[mt][nt][r]);
      }
}

// ---------------------------------------------------------------------------
// Stage 4 (MFMA): align = alignA @ w_off -> bf16 [16384][512]
// Same VGPR-prefetch single-LDS-buffer pipeline; 27.6 KB LDS, grid 1024.
// ---------------------------------------------------------------------------
__global__ __launch_bounds__(256) void gemm_align_mfma(
    const unsigned short* __restrict__ alignA,
    const unsigned short* __restrict__ w_offT,
    unsigned short* __restrict__ alignBf) {
  __shared__ unsigned short As[128][72];
  __shared__ unsigned short Bs[64][72];
  int n0 = blockIdx.x * 64;
  int m0 = blockIdx.y * 128;
  int t = threadIdx.x;
  int wid = t >> 6, lane = t & 63;
  int lrow = lane & 15, lq = lane >> 4;
  f32x4 acc[2][4];
#pragma unroll
  for (int i = 0; i < 2; ++i)
#pragma unroll
    for (int j = 0; j < 4; ++j) acc[i][j] = (f32x4){0.f, 0.f, 0.f, 0.f};

  int arow = t >> 3, ack = t & 7;
  uint4 pa[4], pb[2];
  auto loadA = [&](int k0) {
#pragma unroll
    for (int i = 0; i < 4; ++i)
      pa[i] = *(const uint4*)&alignA[(size_t)(m0 + arow + i * 32) * 512 + k0 + ack * 8];
  };
  auto loadB = [&](int k0) {
#pragma unroll
    for (int i = 0; i < 2; ++i)
      pb[i] = *(const uint4*)&w_offT[(size_t)(n0 + arow + i * 32) * 512 + k0 + ack * 8];
  };
  auto storeT = [&]() {
#pragma unroll
    for (int i = 0; i < 4; ++i)
      *(uint4*)&As[arow + i * 32][ack * 8] = pa[i];
#pragma unroll
    for (int i = 0; i < 2; ++i)
      *(uint4*)&Bs[arow + i * 32][ack * 8] = pb[i];
  };

  loadA(0);
  loadB(0);
  storeT();
  __syncthreads();
  for (int kb = 0; kb < 8; ++kb) {
    bool has_next = (kb + 1) < 8;
    if (has_next) { loadA((kb + 1) * 64); loadB((kb + 1) * 64); }
#pragma unroll
    for (int kk = 0; kk < 2; ++kk) {
      bf16x8 a[2], b[4];
#pragma unroll
      for (int mt = 0; mt < 2; ++mt)
        a[mt] = *(const bf16x8*)&As[wid * 32 + mt * 16 + lrow][kk * 32 + lq * 8];
#pragma unroll
      for (int nt = 0; nt < 4; ++nt)
        b[nt] = *(const bf16x8*)&Bs[nt * 16 + lrow][kk * 32 + lq * 8];
#pragma unroll
      for (int mt = 0; mt < 2; ++mt)
#pragma unroll
        for (int nt = 0; nt < 4; ++nt)
          acc[mt][nt] = __builtin_amdgcn_mfma_f32_16x16x32_bf16(
              a[mt], b[nt], acc[mt][nt], 0, 0, 0);
    }
    if (has_next) {
      __syncthreads();  // readers done
      storeT();         // vmcnt waits here, after MFMA cover
      __syncthreads();
    }
  }
#pragma unroll
  for (int mt = 0; mt < 2; ++mt)
#pragma unroll
    for (int nt = 0; nt < 4; ++nt)
#pragma unroll
      for (int r = 0; r < 4; ++r) {
        int m = m0 + wid * 32 + mt * 16 + lq * 4 + r;
        int n = n0 + nt * 16 + lrow;
        alignBf[(size_t)m * 512 + n] = f2bf(acc[mt][nt][r]);
      }
}

// ---------------------------------------------------------------------------
// Stage 5 (MFMA): om = conv3x3(align) + b_om  as 9 shifted GEMMs.
// R7 structure (measured 106 us): grid (4 nblk x 128 mblk), M=128 x N=64,
// B double-buffered via stageB before MFMA, one barrier/tap; A per c0.
// ---------------------------------------------------------------------------
__global__ __launch_bounds__(256) void om_conv_mfma(
    const unsigned short* __restrict__ alignBf,  // [16384][512] bf16
    const unsigned short* __restrict__ w_omT,    // [9][256 n][512 c] bf16
    const float* __restrict__ b_om,
    float* __restrict__ om) {                    // [16384][216] fp32
  __shared__ unsigned short As[4][66][72];
  __shared__ unsigned short Bs[2][64][72];
  int nblk = blockIdx.x;          // 0..3
  int mblk = blockIdx.y;          // 0..127
  int b = mblk >> 5, hp = mblk & 31;
  int h0 = hp * 2;
  int n0 = nblk * 64;
  int t = threadIdx.x;
  int wid = t >> 6, lane = t & 63;
  int wy = wid >> 1, wx = wid & 1;  // wave: wy = image row, wx = N half
  int lrow = lane & 15, lq = lane >> 4;
  const size_t imgbase = (size_t)b * 4096;
  f32x4 acc[4][2];
#pragma unroll
  for (int i = 0; i < 4; ++i)
#pragma unroll
    for (int j = 0; j < 2; ++j) acc[i][j] = (f32x4){0.f, 0.f, 0.f, 0.f};

  auto stageB = [&](int buf, int tap, int c0) {
    for (int u = t; u < 64 * 8; u += 256) {
      int n = u >> 3, ck = u & 7;
      *(uint4*)&Bs[buf][n][ck * 8] =
          *(const uint4*)&w_omT[((size_t)tap * 256 + n0 + n) * 512 + c0 * 64 + ck * 8];
    }
  };
  auto stageA = [&](int c0) {
    for (int u = t; u < 4 * 66 * 8; u += 256) {
      int dy = u / 528;  // 66*8
      int r = u - dy * 528;
      int px = r >> 3, ck = r & 7;
      int w = px - 1;
      int y = h0 - 1 + dy;
      uint4 v = make_uint4(0u, 0u, 0u, 0u);
      if (w >= 0 && w < 64 && y >= 0 && y < 64)
        v = *(const uint4*)&alignBf[(imgbase + y * 64 + w) * 512 + c0 * 64 + ck * 8];
      *(uint4*)&As[dy][px][ck * 8] = v;
    }
  };

  stageB(0, 0, 0);
  stageA(0);
  __syncthreads();
  int buf = 0;
  for (int c0 = 0; c0 < 8; ++c0) {
    for (int tap = 0; tap < 9; ++tap) {
      // prefetch next B into the other buffer (overlaps with MFMA below)
      int ntap = tap + 1, nc0 = c0;
      if (ntap == 9) { ntap = 0; nc0 = (c0 + 1) & 7; }
      stageB(buf ^ 1, ntap, nc0);
      int dyt = tap / 3, dxt = tap - dyt * 3;
#pragma unroll
      for (int kk = 0; kk < 2; ++kk) {
        bf16x8 a[4], bb[2];
#pragma unroll
        for (int mt = 0; mt < 4; ++mt)
          a[mt] = *(const bf16x8*)&As[wy + dyt][mt * 16 + lrow + dxt][kk * 32 + lq * 8];
#pragma unroll
        for (int nt = 0; nt < 2; ++nt)
          bb[nt] = *(const bf16x8*)&Bs[buf][wx * 32 + nt * 16 + lrow][kk * 32 + lq * 8];
#pragma unroll
        for (int mt = 0; mt < 4; ++mt)
#pragma unroll
          for (int nt = 0; nt < 2; ++nt)
            acc[mt][nt] = __builtin_amdgcn_mfma_f32_16x16x32_bf16(
                a[mt], bb[nt], acc[mt][nt], 0, 0, 0);
      }
      __syncthreads();  // B(next) staged everywhere; MFMA(cur) done everywhere
      buf ^= 1;
    }
    if (c0 < 7) {
      stageA(c0 + 1);
      __syncthreads();
    }
  }
  // epilogue: direct store + bias (n < 216)
#pragma unroll
  for (int nt = 0; nt < 2; ++nt) {
    int n = n0 + wx * 32 + nt * 16 + lrow;
    if (n < OMC) {
      float bias = b_om[n];
#pragma unroll
      for (int mt = 0; mt < 4; ++mt) {
#pragma unroll
        for (int r = 0; r < 4; ++r) {
          size_t m = imgbase + (size_t)(h0 + wy) * 64 + mt * 16 + lq * 4 + r;
          om[m * OMC + n] = acc[mt][nt][r] + bias;
        }
      }
    }
  }
}

// ---------------------------------------------------------------------------
// Stage 6a: deformable sampling -> S[mloc][tap*256+c] bf16 (masked)
// Block = half an image row (32 px), 256 threads. Lane = channel quad.
// ---------------------------------------------------------------------------
__global__ __launch_bounds__(256) void dcn_sample(
    const float* __restrict__ om, const unsigned short* __restrict__ upbf,
    unsigned short* __restrict__ S, int bh0) {
  __shared__ int offsA[256][4];   // [p 32][g 8] corner base offsets (elements)
  __shared__ float wtsA[256][4];  // bilinear weights * mask
  int blk = blockIdx.x;
  int bh = bh0 + (blk >> 1);
  int half = blk & 1;
  int b = bh >> 6, h = bh & 63;
  int p0 = half * 32;                // pixel base within the row
  int m0g = bh * 64 + p0;            // global om row base
  int mloc0 = (bh - bh0) * 64 + p0;  // S row base (chunk-local)
  int t = threadIdx.x;
  const unsigned short* upb = upbf + (size_t)b * HWP * CCH;
  int lane = t & 63;
  int ph = t >> 6;     // 0..3 (wave id) -> 8 pixels each
  int c = lane * 4;    // channel quad
  int g = lane >> 3;   // group of this channel quad
  for (int tap = 0; tap < 9; ++tap) {
    int ky = tap / 3, kx = tap - ky * 3;
    __syncthreads();  // prior-tap readers of offs/wts done
    {
      int p = t >> 3, gg = t & 7;  // p 0..31
      const float* omr = om + (size_t)(m0g + p) * OMC;
      float dy = omr[gg * 18 + tap * 2];
      float dx = omr[gg * 18 + tap * 2 + 1];
      float mk = 1.0f / (1.0f + expf(-omr[144 + gg * 9 + tap]));
      float sy = (float)(h + ky - 1) + dy;
      float sx = (float)(p0 + p + kx - 1) + dx;
      float y0f = floorf(sy), x0f = floorf(sx);
      float fy = sy - y0f, fx = sx - x0f;
      int y0 = (int)y0f, x0 = (int)x0f;
      int y1 = y0 + 1, x1 = x0 + 1;
      float vy0 = (y0 >= 0 && y0 <= 63) ? 1.f : 0.f;
      float vy1 = (y1 >= 0 && y1 <= 63) ? 1.f : 0.f;
      float vx0 = (x0 >= 0 && x0 <= 63) ? 1.f : 0.f;
      float vx1 = (x1 >= 0 && x1 <= 63) ? 1.f : 0.f;
      int yc0 = min(max(y0, 0), 63), yc1 = min(max(y1, 0), 63);
      int xc0 = min(max(x0, 0), 63), xc1 = min(max(x1, 0), 63);
      offsA[t][0] = (yc0 * 64 + xc0) * 256;
      offsA[t][1] = (yc0 * 64 + xc1) * 256;
      offsA[t][2] = (yc1 * 64 + xc0) * 256;
      offsA[t][3] = (yc1 * 64 + xc1) * 256;
      wtsA[t][0] = (1.f - fy) * (1.f - fx) * vy0 * vx0 * mk;
      wtsA[t][1] = (1.f - fy) * fx * vy0 * vx1 * mk;
      wtsA[t][2] = fy * (1.f - fx) * vy1 * vx0 * mk;
      wtsA[t][3] = fy * fx * vy1 * vx1 * mk;
    }
    __syncthreads();
#pragma unroll
    for (int pp = 0; pp < 8; ++pp) {
      int p = ph * 8 + pp;
      int idx = (p << 3) | g;
      int4 o = *(const int4*)&offsA[idx][0];
      float4 wv = *(const float4*)&wtsA[idx][0];
      uint2 u00 = *(const uint2*)&upb[o.x + c];
      uint2 u01 = *(const uint2*)&upb[o.y + c];
      uint2 u10 = *(const uint2*)&upb[o.z + c];
      uint2 u11 = *(const uint2*)&upb[o.w + c];
      float a0, a1, a2, a3, b0, b1, b2, b3, c0, c1, c2, c3, d0, d1, d2, d3;
      bfpair(u00.x, a0, a1); bfpair(u00.y, a2, a3);
      bfpair(u01.x, b0, b1); bfpair(u01.y, b2, b3);
      bfpair(u10.x, c0, c1); bfpair(u10.y, c2, c3);
      bfpair(u11.x, d0, d1); bfpair(u11.y, d2, d3);
      float v0 = wv.x * a0 + wv.y * b0 + wv.z * c0 + wv.w * d0;
      float v1 = wv.x * a1 + wv.y * b1 + wv.z * c1 + wv.w * d1;
      float v2 = wv.x * a2 + wv.y * b2 + wv.z * c2 + wv.w * d2;
      float v3 = wv.x * a3 + wv.y * b3 + wv.z * c3 + wv.w * d3;
      uint2 outv;
      outv.x = (unsigned int)f2bf(v0) | ((unsigned int)f2bf(v1) << 16);
      outv.y = (unsigned int)f2bf(v2) | ((unsigned int)f2bf(v3) << 16);
      *(uint2*)&S[(size_t)(mloc0 + p) * KDC + tap * 256 + c] = outv;
    }
  }
}

// ---------------------------------------------------------------------------
// Stage 6b (MFMA): out = relu(S @ w_dcnT + b_dcn) + finecal
// Tile M=64 x N=128 -> 512 blocks, 2 blocks/CU. 4 waves of 32x64.
// VGPR prefetch + LDS dbuf, ONE barrier per K-iter.
// ---------------------------------------------------------------------------
__global__ __launch_bounds__(256) void dcn_gemm(
    const unsigned short* __restrict__ S,       // [Mloc][2304]
    const unsigned short* __restrict__ w_dcnT,  // [9][256 f][256 c]
    const float* __restrict__ b_dcn,
    const float* __restrict__ finecal,
    float* __restrict__ outp, int m_base, int kiters) {
  __shared__ unsigned short As[2][64][72];      // 18.4 KB
  __shared__ unsigned short Bs[2][128][72];     // 36.9 KB
  int n0 = blockIdx.x * 128;
  int mloc0 = blockIdx.y * 64;
  int m0 = m_base + mloc0;
  int t = threadIdx.x;
  int wid = t >> 6, lane = t & 63;
  int wy = wid >> 1, wx = wid & 1;   // wave: 32-row half x 64-col half
  int lrow = lane & 15, lq = lane >> 4;
  f32x4 acc[2][4];
#pragma unroll
  for (int i = 0; i < 2; ++i)
#pragma unroll
    for (int j = 0; j < 4; ++j) acc[i][j] = (f32x4){0.f, 0.f, 0.f, 0.f};

  int arow = t >> 3, ack = t & 7;  // A rows arow, arow+32 ; B rows +0..96
  uint4 pa[2], pb[4];
  auto loadA = [&](int k0, uint4* p) {
#pragma unroll
    for (int i = 0; i < 2; ++i)
      p[i] = *(const uint4*)&S[(size_t)(mloc0 + arow + i * 32) * KDC + k0 + ack * 8];
  };
  auto loadB = [&](int k0, uint4* p) {
    int tap = k0 >> 8, c0 = k0 & 255;
#pragma unroll
    for (int i = 0; i < 4; ++i)
      p[i] = *(const uint4*)&w_dcnT[((size_t)tap * 256 + n0 + arow + i * 32) * 256 + c0 + ack * 8];
  };
  auto storeTiles = [&](int buf, const uint4* a, const uint4* b) {
#pragma unroll
    for (int i = 0; i < 2; ++i)
      *(uint4*)&As[buf][arow + i * 32][ack * 8] = a[i];
#pragma unroll
    for (int i = 0; i < 4; ++i)
      *(uint4*)&Bs[buf][arow + i * 32][ack * 8] = b[i];
  };

  loadA(0, pa);
  loadB(0, pb);
  storeTiles(0, pa, pb);
  __syncthreads();
  int buf = 0;
  for (int kb = 0; kb < kiters; ++kb) {
    bool has_next = (kb + 1) < kiters;
    if (has_next) {
      loadA((kb + 1) * 64, pa);   // in flight during MFMA below
      loadB((kb + 1) * 64, pb);
    }
#pragma unroll
    for (int kk = 0; kk < 2; ++kk) {
      bf16x8 a[2], b[4];
#pragma unroll
      for (int mt = 0; mt < 2; ++mt)
        a[mt] = *(const bf16x8*)&As[buf][wy * 32 + mt * 16 + lrow][kk * 32 + lq * 8];
#pragma unroll
      for (int nt = 0; nt < 4; ++nt)
        b[nt] = *(const bf16x8*)&Bs[buf][wx * 64 + nt * 16 + lrow][kk * 32 + lq * 8];
#pragma unroll
      for (int mt = 0; mt < 2; ++mt)
#pragma unroll
        for (int nt = 0; nt < 4; ++nt)
          acc[mt][nt] = __builtin_amdgcn_mfma_f32_16x16x32_bf16(
              a[mt], b[nt], acc[mt][nt], 0, 0, 0);
    }
    if (has_next) {
      storeTiles(buf ^ 1, pa, pb);  // waits vmcnt here, after MFMA cover
      __syncthreads();
      buf ^= 1;
    }
  }
#pragma unroll
  for (int mt = 0; mt < 2; ++mt)
#pragma unroll
    for (int nt = 0; nt < 4; ++nt) {
      int f = n0 + wx * 64 + nt * 16 + lrow;
      float bias = b_dcn[f];
#pragma unroll
      for (int r = 0; r < 4; ++r) {
        int m = m0 + wy * 32 + mt * 16 + lq * 4 + r;
        float v = fmaxf(acc[mt][nt][r] + bias, 0.f);
        float fc = __builtin_nontemporal_load(&finecal[(size_t)m * 256 + f]);
        __builtin_nontemporal_store(v + fc, &outp[(size_t)m * 256 + f]);
      }
    }
}

// ---------------------------------------------------------------------------
extern "C" void kernel_launch(void* const* d_in, const int* in_sizes, int n_in,
                              void* d_out, int out_size, void* d_ws, size_t ws_size,
                              hipStream_t stream) {
  const float* coarse = (const float*)d_in[0];
  const float* fine   = (const float*)d_in[1];
  const float* w_att  = (const float*)d_in[2];
  const float* w_sel  = (const float*)d_in[3];
  const float* w_off  = (const float*)d_in[4];
  const float* w_om   = (const float*)d_in[5];
  const float* b_om   = (const float*)d_in[6];
  const float* w_dcn  = (const float*)d_in[7];
  const float* b_dcn  = (const float*)d_in[8];
  float* outp = (float*)d_out;

  char* base = (char*)d_ws;
  size_t o = 0;
  float* scale            = (float*)(base + o);          o += 4096;
  float* finecal          = (float*)(base + o);          o += 16777216;
  float* omb              = (float*)(base + o);          o += 14155776;
  unsigned short* upbf    = (unsigned short*)(base + o); o += 8388608;
  unsigned short* w_offT  = (unsigned short*)(base + o); o += 524288;
  unsigned short* w_omT   = (unsigned short*)(base + o); o += 2359296;  // 9*256*512
  unsigned short* w_selT  = (unsigned short*)(base + o); o += 131072;
  unsigned short* w_dcnT  = (unsigned short*)(base + o); o += 1179648;
  unsigned short* Sbuf    = (unsigned short*)(base + o);  // S region
  size_t fixed = o;
  // alignA/alignBf alias the S region (dead before S is written):
  unsigned short* alignA  = Sbuf;
  unsigned short* alignBf = (unsigned short*)((char*)Sbuf + 16777216);
  // partial pooling buffer aliases omb (dead until om_conv writes it)
  float* partial = omb;

  bool fullS = (ws_size >= fixed + 75497472);  // constant across calls

  prep_weights<<<dim3(4608), dim3(256), 0, stream>>>(
      w_off, w_om, w_sel, w_dcn, w_offT, w_omT, w_selT, w_dcnT);
  pool_partial<<<dim3(64, 4), dim3(256), 0, stream>>>(fine, partial);
  pool_finish<<<dim3(4), dim3(256), 0, stream>>>(partial, w_att, scale);
  upsample_kernel<<<dim3(16384), dim3(256), 0, stream>>>(coarse, upbf, alignA);
  gemm_finecal_mfma<<<dim3(4, 128), dim3(256), 0, stream>>>(
      fine, scale, w_selT, finecal, alignA);
  gemm_align_mfma<<<dim3(8, 128), dim3(256), 0, stream>>>(alignA, w_offT, alignBf);
  om_conv_mfma<<<dim3(4, 128), dim3(256), 0, stream>>>(alignBf, w_omT, b_om, omb);

  if (fullS) {
    dcn_sample<<<dim3(512), dim3(256), 0, stream>>>(omb, upbf, Sbuf, 0);
    dcn_gemm<<<dim3(2, 256), dim3(256), 0, stream>>>(
        Sbuf, w_dcnT, b_dcn, finecal, outp, 0, KDC / 64);
  } else {
    // chunked: 2 batches (8192 rows of S) at a time; S region = 37.7 MB
    for (int ch = 0; ch < 2; ++ch) {
      dcn_sample<<<dim3(256), dim3(256), 0, stream>>>(omb, upbf, Sbuf, ch * 128);
      dcn_gemm<<<dim3(2, 128), dim3(256), 0, stream>>>(
          Sbuf, w_dcnT, b_dcn, finecal, outp, ch * 8192, KDC / 64);
    }
  }
}

// Round 11
// 398.226 us; speedup vs baseline: 1.1337x; 1.1337x over previous
//
#include <hip/hip_runtime.h>
#include <hip/hip_bf16.h>
#include <cstddef>

// Shapes (fixed): B=4, H=W=64, C=256, G=8, K=9.
constexpr int HWP = 64 * 64;
constexpr int CCH = 256;
constexpr int OMC = 216;   // G*3*K
constexpr int KDC = 2304;  // 9*256

typedef __attribute__((ext_vector_type(8))) short bf16x8;
typedef __attribute__((ext_vector_type(4))) float f32x4;

__device__ inline unsigned short f2bf(float x) {
  __hip_bfloat16 h = __float2bfloat16(x);
  return *reinterpret_cast<unsigned short*>(&h);
}
__device__ inline float bf2f(unsigned short u) {
  unsigned int v = ((unsigned int)u) << 16;
  return __uint_as_float(v);
}
// unpack a uint holding two bf16: lo -> a, hi -> b
__device__ inline void bfpair(unsigned int u, float& a, float& b) {
  a = __uint_as_float(u << 16);
  b = __uint_as_float(u & 0xffff0000u);
}

// ---------------------------------------------------------------------------
// prep (tiled transpose, coalesced both sides):
//   w_offT[512 n][512 k] ; w_omT[9][256 n(pad)][512 c] ; w_selT[256 n][256 k];
//   w_dcnT[9][256 f][256 c]   (all bf16)
// 32x32 fp32 tile in LDS; 256 thr; each thread 4 elements.
// blocks: 256 (w_off) + 64 (w_sel) + 576 (w_dcn) + 1152 (w_om) = 2048
// ---------------------------------------------------------------------------
__global__ __launch_bounds__(256) void prep_transpose(
    const float* __restrict__ w_off, const float* __restrict__ w_om,
    const float* __restrict__ w_sel, const float* __restrict__ w_dcn,
    unsigned short* __restrict__ w_offT, unsigned short* __restrict__ w_omT,
    unsigned short* __restrict__ w_selT, unsigned short* __restrict__ w_dcnT) {
  __shared__ float tile[32][33];
  int bid = blockIdx.x;
  int t = threadIdx.x;
  const float* src;
  unsigned short* dst;
  int in_rs, out_rs, r0, c0, cmax;
  if (bid < 256) {               // w_off: in[512 k][512 n] -> out[n][k]
    int tr = bid >> 4, tc = bid & 15;
    src = w_off; dst = w_offT; in_rs = 512; out_rs = 512;
    r0 = tr * 32; c0 = tc * 32; cmax = 512;
  } else if (bid < 320) {        // w_sel: in[256 k][256 n] -> out[n][k]
    int b2 = bid - 256;
    int tr = b2 >> 3, tc = b2 & 7;
    src = w_sel; dst = w_selT; in_rs = 256; out_rs = 256;
    r0 = tr * 32; c0 = tc * 32; cmax = 256;
  } else if (bid < 896) {        // w_dcn: 9 x in[256 c][256 f] -> out[tap][f][c]
    int b2 = bid - 320;
    int tap = b2 >> 6; b2 &= 63;
    int tr = b2 >> 3, tc = b2 & 7;
    src = w_dcn + (size_t)tap * 65536; dst = w_dcnT + (size_t)tap * 65536;
    in_rs = 256; out_rs = 256;
    r0 = tr * 32; c0 = tc * 32; cmax = 256;
  } else {                       // w_om: 9 x in[512 c][216 n] -> out[tap][256 n][512 c]
    int b2 = bid - 896;
    int tap = b2 >> 7; b2 &= 127;   // 16 r-tiles x 8 c-tiles
    int tr = b2 >> 3, tc = b2 & 7;
    src = w_om + (size_t)tap * 512 * 216; dst = w_omT + (size_t)tap * 256 * 512;
    in_rs = 216; out_rs = 512;
    r0 = tr * 32; c0 = tc * 32; cmax = 216;
  }
  int row = t >> 3, c4 = (t & 7) * 4;
#pragma unroll
  for (int j = 0; j < 4; ++j) {
    int cc = c0 + c4 + j;
    tile[row][c4 + j] = (cc < cmax) ? src[(size_t)(r0 + row) * in_rs + cc] : 0.f;
  }
  __syncthreads();
  ushort4 v;
  v.x = f2bf(tile[c4 + 0][row]);
  v.y = f2bf(tile[c4 + 1][row]);
  v.z = f2bf(tile[c4 + 2][row]);
  v.w = f2bf(tile[c4 + 3][row]);
  *(ushort4*)&dst[(size_t)(c0 + row) * out_rs + r0 + c4] = v;
}

// ---------------------------------------------------------------------------
// Stage 1a/1b: pooled mean (parallel) + attn matvec + sigmoid
// ---------------------------------------------------------------------------
__global__ __launch_bounds__(256) void pool_partial(
    const float* __restrict__ fine, float* __restrict__ partial) {
  int r = blockIdx.x;  // 0..63
  int b = blockIdx.y;  // 0..3
  int t = threadIdx.x;
  const float* src = fine + ((size_t)b * 4096 + r * 64) * 256 + t;
  float s = 0.f;
#pragma unroll 8
  for (int p = 0; p < 64; ++p) s += src[(size_t)p * 256];
  partial[((size_t)b * 64 + r) * 256 + t] = s;
}

__global__ __launch_bounds__(256) void pool_finish(
    const float* __restrict__ partial, const float* __restrict__ w_att,
    float* __restrict__ scale) {
  __shared__ float pl[256];
  int b = blockIdx.x;
  int t = threadIdx.x;
  const float* pp = partial + (size_t)b * 64 * 256 + t;
  float s = 0.f;
#pragma unroll 8
  for (int r = 0; r < 64; ++r) s += pp[(size_t)r * 256];
  pl[t] = s * (1.0f / 4096.0f);
  __syncthreads();
  float acc = 0.f;
  for (int ci = 0; ci < 256; ++ci) acc += pl[ci] * w_att[ci * 256 + t];
  scale[b * 256 + t] = 1.0f + 1.0f / (1.0f + expf(-acc));
}

// ---------------------------------------------------------------------------
// Stage 2: bilinear upsample 32->64 -> upbf (bf16, for dcn sampling) and
//          bf16 2*up into alignA cols 256..511
// ---------------------------------------------------------------------------
__global__ __launch_bounds__(256) void upsample_kernel(
    const float* __restrict__ coarse, unsigned short* __restrict__ upbf,
    unsigned short* __restrict__ alignA) {
  int m = blockIdx.x;  // b*4096 + h*64 + w
  int c = threadIdx.x;
  int b = m >> 12, h = (m >> 6) & 63, w = m & 63;
  float cy = fminf(fmaxf(h * 0.5f - 0.25f, 0.f), 31.f);
  float cx = fminf(fmaxf(w * 0.5f - 0.25f, 0.f), 31.f);
  int y0 = (int)cy, x0 = (int)cx;
  float fy = cy - y0, fx = cx - x0;
  int y1 = min(y0 + 1, 31), x1 = min(x0 + 1, 31);
  const float* base = coarse + (size_t)b * 32 * 32 * CCH;
  float v00 = base[(y0 * 32 + x0) * CCH + c];
  float v01 = base[(y0 * 32 + x1) * CCH + c];
  float v10 = base[(y1 * 32 + x0) * CCH + c];
  float v11 = base[(y1 * 32 + x1) * CCH + c];
  float top = v00 + (v01 - v00) * fx;
  float bot = v10 + (v11 - v10) * fx;
  float v = top + (bot - top) * fy;
  upbf[(size_t)m * CCH + c] = f2bf(v);
  alignA[(size_t)m * 512 + 256 + c] = f2bf(2.f * v);
}

// ---------------------------------------------------------------------------
// Stage 3 (MFMA): fine_cal = (fine*scale) @ w_sel -> fp32 finecal (residual)
//                 + bf16 copy into alignA cols 0..255.  Tile 128x64, BK=64.
// Simple 2-barrier staging (measured best at this occupancy).
// ---------------------------------------------------------------------------
__global__ __launch_bounds__(256) void gemm_finecal_mfma(
    const float* __restrict__ fine, const float* __restrict__ scale,
    const unsigned short* __restrict__ w_selT,   // [256 n][256 k]
    float* __restrict__ finecal, unsigned short* __restrict__ alignA) {
  __shared__ unsigned short As[128][72];
  __shared__ unsigned short Bs[64][72];
  __shared__ float sc[256];
  int n0 = blockIdx.x * 64;
  int m0 = blockIdx.y * 128;
  int t = threadIdx.x;
  int wid = t >> 6, lane = t & 63;
  int lrow = lane & 15, lq = lane >> 4;
  int bb = m0 >> 12;  // 128 | 4096: no batch straddle
  sc[t] = scale[bb * 256 + t];
  f32x4 acc[2][4];
#pragma unroll
  for (int i = 0; i < 2; ++i)
#pragma unroll
    for (int j = 0; j < 4; ++j) acc[i][j] = (f32x4){0.f, 0.f, 0.f, 0.f};
  for (int k0 = 0; k0 < 256; k0 += 64) {
    __syncthreads();  // also covers sc[] on first iteration
    for (int u = t; u < 128 * 8; u += 256) {
      int row = u >> 3, ck = u & 7;
      const float* fp = &fine[(size_t)(m0 + row) * 256 + k0 + ck * 8];
      float4 f0 = *(const float4*)fp;
      float4 f1 = *(const float4*)(fp + 4);
      int kb = k0 + ck * 8;
      ushort4 u0 = make_ushort4(f2bf(f0.x * sc[kb]), f2bf(f0.y * sc[kb + 1]),
                                f2bf(f0.z * sc[kb + 2]), f2bf(f0.w * sc[kb + 3]));
      ushort4 u1 = make_ushort4(f2bf(f1.x * sc[kb + 4]), f2bf(f1.y * sc[kb + 5]),
                                f2bf(f1.z * sc[kb + 6]), f2bf(f1.w * sc[kb + 7]));
      *(ushort4*)&As[row][ck * 8] = u0;
      *(ushort4*)&As[row][ck * 8 + 4] = u1;
    }
    for (int u = t; u < 64 * 8; u += 256) {
      int row = u >> 3, ck = u & 7;
      *(uint4*)&Bs[row][ck * 8] = *(const uint4*)&w_selT[(size_t)(n0 + row) * 256 + k0 + ck * 8];
    }
    __syncthreads();
#pragma unroll
    for (int kk = 0; kk < 2; ++kk) {
      bf16x8 a[2], b[4];
#pragma unroll
      for (int mt = 0; mt < 2; ++mt)
        a[mt] = *(const bf16x8*)&As[wid * 32 + mt * 16 + lrow][kk * 32 + lq * 8];
#pragma unroll
      for (int nt = 0; nt < 4; ++nt)
        b[nt] = *(const bf16x8*)&Bs[nt * 16 + lrow][kk * 32 + lq * 8];
#pragma unroll
      for (int mt = 0; mt < 2; ++mt)
#pragma unroll
        for (int nt = 0; nt < 4; ++nt)
          acc[mt][nt] = __builtin_amdgcn_mfma_f32_16x16x32_bf16(
              a[mt], b[nt], acc[mt][nt], 0, 0, 0);
    }
  }
#pragma unroll
  for (int mt = 0; mt < 2; ++mt)
#pragma unroll
    for (int nt = 0; nt < 4; ++nt)
#pragma unroll
      for (int r = 0; r < 4; ++r) {
        int m = m0 + wid * 32 + mt * 16 + lq * 4 + r;
        int n = n0 + nt * 16 + lrow;
        finecal[(size_t)m * 256 + n] = acc[mt][nt][r];
        alignA[(size_t)m * 512 + n] = f2bf(acc[mt][nt][r]);
      }
}

// ---------------------------------------------------------------------------
// Stage 4 (MFMA): align = alignA @ w_off -> bf16 [16384][512]
// Simple 2-barrier staging (measured best at this occupancy).
// ---------------------------------------------------------------------------
__global__ __launch_bounds__(256) void gemm_align_mfma(
    const unsigned short* __restrict__ alignA,
    const unsigned short* __restrict__ w_offT,
    unsigned short* __restrict__ alignBf) {
  __shared__ unsigned short As[128][72];
  __shared__ unsigned short Bs[64][72];
  int n0 = blockIdx.x * 64;
  int m0 = blockIdx.y * 128;
  int t = threadIdx.x;
  int wid = t >> 6, lane = t & 63;
  int lrow = lane & 15, lq = lane >> 4;
  f32x4 acc[2][4];
#pragma unroll
  for (int i = 0; i < 2; ++i)
#pragma unroll
    for (int j = 0; j < 4; ++j) acc[i][j] = (f32x4){0.f, 0.f, 0.f, 0.f};
  for (int k0 = 0; k0 < 512; k0 += 64) {
    __syncthreads();
    for (int u = t; u < 128 * 8; u += 256) {
      int row = u >> 3, ck = u & 7;
      *(uint4*)&As[row][ck * 8] =
          *(const uint4*)&alignA[(size_t)(m0 + row) * 512 + k0 + ck * 8];
    }
    for (int u = t; u < 64 * 8; u += 256) {
      int row = u >> 3, ck = u & 7;
      *(uint4*)&Bs[row][ck * 8] =
          *(const uint4*)&w_offT[(size_t)(n0 + row) * 512 + k0 + ck * 8];
    }
    __syncthreads();
#pragma unroll
    for (int kk = 0; kk < 2; ++kk) {
      bf16x8 a[2], b[4];
#pragma unroll
      for (int mt = 0; mt < 2; ++mt)
        a[mt] = *(const bf16x8*)&As[wid * 32 + mt * 16 + lrow][kk * 32 + lq * 8];
#pragma unroll
      for (int nt = 0; nt < 4; ++nt)
        b[nt] = *(const bf16x8*)&Bs[nt * 16 + lrow][kk * 32 + lq * 8];
#pragma unroll
      for (int mt = 0; mt < 2; ++mt)
#pragma unroll
        for (int nt = 0; nt < 4; ++nt)
          acc[mt][nt] = __builtin_amdgcn_mfma_f32_16x16x32_bf16(
              a[mt], b[nt], acc[mt][nt], 0, 0, 0);
    }
  }
#pragma unroll
  for (int mt = 0; mt < 2; ++mt)
#pragma unroll
    for (int nt = 0; nt < 4; ++nt)
#pragma unroll
      for (int r = 0; r < 4; ++r) {
        int m = m0 + wid * 32 + mt * 16 + lq * 4 + r;
        int n = n0 + nt * 16 + lrow;
        alignBf[(size_t)m * 512 + n] = f2bf(acc[mt][nt][r]);
      }
}

// ---------------------------------------------------------------------------
// Stage 5 (MFMA): om = conv3x3(align) + b_om  as 9 shifted GEMMs.
// R7 structure (measured 106 us): grid (4 nblk x 128 mblk), M=128 x N=64,
// B double-buffered via stageB before MFMA, one barrier/tap; A per c0.
// ---------------------------------------------------------------------------
__global__ __launch_bounds__(256) void om_conv_mfma(
    const unsigned short* __restrict__ alignBf,  // [16384][512] bf16
    const unsigned short* __restrict__ w_omT,    // [9][256 n][512 c] bf16
    const float* __restrict__ b_om,
    float* __restrict__ om) {                    // [16384][216] fp32
  __shared__ unsigned short As[4][66][72];
  __shared__ unsigned short Bs[2][64][72];
  int nblk = blockIdx.x;          // 0..3
  int mblk = blockIdx.y;          // 0..127
  int b = mblk >> 5, hp = mblk & 31;
  int h0 = hp * 2;
  int n0 = nblk * 64;
  int t = threadIdx.x;
  int wid = t >> 6, lane = t & 63;
  int wy = wid >> 1, wx = wid & 1;  // wave: wy = image row, wx = N half
  int lrow = lane & 15, lq = lane >> 4;
  const size_t imgbase = (size_t)b * 4096;
  f32x4 acc[4][2];
#pragma unroll
  for (int i = 0; i < 4; ++i)
#pragma unroll
    for (int j = 0; j < 2; ++j) acc[i][j] = (f32x4){0.f, 0.f, 0.f, 0.f};

  auto stageB = [&](int buf, int tap, int c0) {
    for (int u = t; u < 64 * 8; u += 256) {
      int n = u >> 3, ck = u & 7;
      *(uint4*)&Bs[buf][n][ck * 8] =
          *(const uint4*)&w_omT[((size_t)tap * 256 + n0 + n) * 512 + c0 * 64 + ck * 8];
    }
  };
  auto stageA = [&](int c0) {
    for (int u = t; u < 4 * 66 * 8; u += 256) {
      int dy = u / 528;  // 66*8
      int r = u - dy * 528;
      int px = r >> 3, ck = r & 7;
      int w = px - 1;
      int y = h0 - 1 + dy;
      uint4 v = make_uint4(0u, 0u, 0u, 0u);
      if (w >= 0 && w < 64 && y >= 0 && y < 64)
        v = *(const uint4*)&alignBf[(imgbase + y * 64 + w) * 512 + c0 * 64 + ck * 8];
      *(uint4*)&As[dy][px][ck * 8] = v;
    }
  };

  stageB(0, 0, 0);
  stageA(0);
  __syncthreads();
  int buf = 0;
  for (int c0 = 0; c0 < 8; ++c0) {
    for (int tap = 0; tap < 9; ++tap) {
      // prefetch next B into the other buffer (overlaps with MFMA below)
      int ntap = tap + 1, nc0 = c0;
      if (ntap == 9) { ntap = 0; nc0 = (c0 + 1) & 7; }
      stageB(buf ^ 1, ntap, nc0);
      int dyt = tap / 3, dxt = tap - dyt * 3;
#pragma unroll
      for (int kk = 0; kk < 2; ++kk) {
        bf16x8 a[4], bb[2];
#pragma unroll
        for (int mt = 0; mt < 4; ++mt)
          a[mt] = *(const bf16x8*)&As[wy + dyt][mt * 16 + lrow + dxt][kk * 32 + lq * 8];
#pragma unroll
        for (int nt = 0; nt < 2; ++nt)
          bb[nt] = *(const bf16x8*)&Bs[buf][wx * 32 + nt * 16 + lrow][kk * 32 + lq * 8];
#pragma unroll
        for (int mt = 0; mt < 4; ++mt)
#pragma unroll
          for (int nt = 0; nt < 2; ++nt)
            acc[mt][nt] = __builtin_amdgcn_mfma_f32_16x16x32_bf16(
                a[mt], bb[nt], acc[mt][nt], 0, 0, 0);
      }
      __syncthreads();  // B(next) staged everywhere; MFMA(cur) done everywhere
      buf ^= 1;
    }
    if (c0 < 7) {
      stageA(c0 + 1);
      __syncthreads();
    }
  }
  // epilogue: direct store + bias (n < 216)
#pragma unroll
  for (int nt = 0; nt < 2; ++nt) {
    int n = n0 + wx * 32 + nt * 16 + lrow;
    if (n < OMC) {
      float bias = b_om[n];
#pragma unroll
      for (int mt = 0; mt < 4; ++mt) {
#pragma unroll
        for (int r = 0; r < 4; ++r) {
          size_t m = imgbase + (size_t)(h0 + wy) * 64 + mt * 16 + lq * 4 + r;
          om[m * OMC + n] = acc[mt][nt][r] + bias;
        }
      }
    }
  }
}

// ---------------------------------------------------------------------------
// Stage 6a: deformable sampling -> S[mloc][tap*256+c] bf16 (masked)
// Block = half an image row (32 px), 256 threads. Lane = channel quad.
// ---------------------------------------------------------------------------
__global__ __launch_bounds__(256) void dcn_sample(
    const float* __restrict__ om, const unsigned short* __restrict__ upbf,
    unsigned short* __restrict__ S, int bh0) {
  __shared__ int offsA[256][4];   // [p 32][g 8] corner base offsets (elements)
  __shared__ float wtsA[256][4];  // bilinear weights * mask
  int blk = blockIdx.x;
  int bh = bh0 + (blk >> 1);
  int half = blk & 1;
  int b = bh >> 6, h = bh & 63;
  int p0 = half * 32;                // pixel base within the row
  int m0g = bh * 64 + p0;            // global om row base
  int mloc0 = (bh - bh0) * 64 + p0;  // S row base (chunk-local)
  int t = threadIdx.x;
  const unsigned short* upb = upbf + (size_t)b * HWP * CCH;
  int lane = t & 63;
  int ph = t >> 6;     // 0..3 (wave id) -> 8 pixels each
  int c = lane * 4;    // channel quad
  int g = lane >> 3;   // group of this channel quad
  for (int tap = 0; tap < 9; ++tap) {
    int ky = tap / 3, kx = tap - ky * 3;
    __syncthreads();  // prior-tap readers of offs/wts done
    {
      int p = t >> 3, gg = t & 7;  // p 0..31
      const float* omr = om + (size_t)(m0g + p) * OMC;
      float dy = omr[gg * 18 + tap * 2];
      float dx = omr[gg * 18 + tap * 2 + 1];
      float mk = 1.0f / (1.0f + expf(-omr[144 + gg * 9 + tap]));
      float sy = (float)(h + ky - 1) + dy;
      float sx = (float)(p0 + p + kx - 1) + dx;
      float y0f = floorf(sy), x0f = floorf(sx);
      float fy = sy - y0f, fx = sx - x0f;
      int y0 = (int)y0f, x0 = (int)x0f;
      int y1 = y0 + 1, x1 = x0 + 1;
      float vy0 = (y0 >= 0 && y0 <= 63) ? 1.f : 0.f;
      float vy1 = (y1 >= 0 && y1 <= 63) ? 1.f : 0.f;
      float vx0 = (x0 >= 0 && x0 <= 63) ? 1.f : 0.f;
      float vx1 = (x1 >= 0 && x1 <= 63) ? 1.f : 0.f;
      int yc0 = min(max(y0, 0), 63), yc1 = min(max(y1, 0), 63);
      int xc0 = min(max(x0, 0), 63), xc1 = min(max(x1, 0), 63);
      offsA[t][0] = (yc0 * 64 + xc0) * 256;
      offsA[t][1] = (yc0 * 64 + xc1) * 256;
      offsA[t][2] = (yc1 * 64 + xc0) * 256;
      offsA[t][3] = (yc1 * 64 + xc1) * 256;
      wtsA[t][0] = (1.f - fy) * (1.f - fx) * vy0 * vx0 * mk;
      wtsA[t][1] = (1.f - fy) * fx * vy0 * vx1 * mk;
      wtsA[t][2] = fy * (1.f - fx) * vy1 * vx0 * mk;
      wtsA[t][3] = fy * fx * vy1 * vx1 * mk;
    }
    __syncthreads();
#pragma unroll
    for (int pp = 0; pp < 8; ++pp) {
      int p = ph * 8 + pp;
      int idx = (p << 3) | g;
      int4 o = *(const int4*)&offsA[idx][0];
      float4 wv = *(const float4*)&wtsA[idx][0];
      uint2 u00 = *(const uint2*)&upb[o.x + c];
      uint2 u01 = *(const uint2*)&upb[o.y + c];
      uint2 u10 = *(const uint2*)&upb[o.z + c];
      uint2 u11 = *(const uint2*)&upb[o.w + c];
      float a0, a1, a2, a3, b0, b1, b2, b3, c0, c1, c2, c3, d0, d1, d2, d3;
      bfpair(u00.x, a0, a1); bfpair(u00.y, a2, a3);
      bfpair(u01.x, b0, b1); bfpair(u01.y, b2, b3);
      bfpair(u10.x, c0, c1); bfpair(u10.y, c2, c3);
      bfpair(u11.x, d0, d1); bfpair(u11.y, d2, d3);
      float v0 = wv.x * a0 + wv.y * b0 + wv.z * c0 + wv.w * d0;
      float v1 = wv.x * a1 + wv.y * b1 + wv.z * c1 + wv.w * d1;
      float v2 = wv.x * a2 + wv.y * b2 + wv.z * c2 + wv.w * d2;
      float v3 = wv.x * a3 + wv.y * b3 + wv.z * c3 + wv.w * d3;
      uint2 outv;
      outv.x = (unsigned int)f2bf(v0) | ((unsigned int)f2bf(v1) << 16);
      outv.y = (unsigned int)f2bf(v2) | ((unsigned int)f2bf(v3) << 16);
      *(uint2*)&S[(size_t)(mloc0 + p) * KDC + tap * 256 + c] = outv;
    }
  }
}

// ---------------------------------------------------------------------------
// Stage 6b (MFMA): out = relu(S @ w_dcnT + b_dcn) + finecal
// Tile M=64 x N=128 -> 512 blocks, 2 blocks/CU. 4 waves of 32x64.
// VGPR prefetch + LDS dbuf, ONE barrier per K-iter.
// ---------------------------------------------------------------------------
__global__ __launch_bounds__(256) void dcn_gemm(
    const unsigned short* __restrict__ S,       // [Mloc][2304]
    const unsigned short* __restrict__ w_dcnT,  // [9][256 f][256 c]
    const float* __restrict__ b_dcn,
    const float* __restrict__ finecal,
    float* __restrict__ outp, int m_base, int kiters) {
  __shared__ unsigned short As[2][64][72];      // 18.4 KB
  __shared__ unsigned short Bs[2][128][72];     // 36.9 KB
  int n0 = blockIdx.x * 128;
  int mloc0 = blockIdx.y * 64;
  int m0 = m_base + mloc0;
  int t = threadIdx.x;
  int wid = t >> 6, lane = t & 63;
  int wy = wid >> 1, wx = wid & 1;   // wave: 32-row half x 64-col half
  int lrow = lane & 15, lq = lane >> 4;
  f32x4 acc[2][4];
#pragma unroll
  for (int i = 0; i < 2; ++i)
#pragma unroll
    for (int j = 0; j < 4; ++j) acc[i][j] = (f32x4){0.f, 0.f, 0.f, 0.f};

  int arow = t >> 3, ack = t & 7;  // A rows arow, arow+32 ; B rows +0..96
  uint4 pa[2], pb[4];
  auto loadA = [&](int k0, uint4* p) {
#pragma unroll
    for (int i = 0; i < 2; ++i)
      p[i] = *(const uint4*)&S[(size_t)(mloc0 + arow + i * 32) * KDC + k0 + ack * 8];
  };
  auto loadB = [&](int k0, uint4* p) {
    int tap = k0 >> 8, c0 = k0 & 255;
#pragma unroll
    for (int i = 0; i < 4; ++i)
      p[i] = *(const uint4*)&w_dcnT[((size_t)tap * 256 + n0 + arow + i * 32) * 256 + c0 + ack * 8];
  };
  auto storeTiles = [&](int buf, const uint4* a, const uint4* b) {
#pragma unroll
    for (int i = 0; i < 2; ++i)
      *(uint4*)&As[buf][arow + i * 32][ack * 8] = a[i];
#pragma unroll
    for (int i = 0; i < 4; ++i)
      *(uint4*)&Bs[buf][arow + i * 32][ack * 8] = b[i];
  };

  loadA(0, pa);
  loadB(0, pb);
  storeTiles(0, pa, pb);
  __syncthreads();
  int buf = 0;
  for (int kb = 0; kb < kiters; ++kb) {
    bool has_next = (kb + 1) < kiters;
    if (has_next) {
      loadA((kb + 1) * 64, pa);   // in flight during MFMA below
      loadB((kb + 1) * 64, pb);
    }
#pragma unroll
    for (int kk = 0; kk < 2; ++kk) {
      bf16x8 a[2], b[4];
#pragma unroll
      for (int mt = 0; mt < 2; ++mt)
        a[mt] = *(const bf16x8*)&As[buf][wy * 32 + mt * 16 + lrow][kk * 32 + lq * 8];
#pragma unroll
      for (int nt = 0; nt < 4; ++nt)
        b[nt] = *(const bf16x8*)&Bs[buf][wx * 64 + nt * 16 + lrow][kk * 32 + lq * 8];
#pragma unroll
      for (int mt = 0; mt < 2; ++mt)
#pragma unroll
        for (int nt = 0; nt < 4; ++nt)
          acc[mt][nt] = __builtin_amdgcn_mfma_f32_16x16x32_bf16(
              a[mt], b[nt], acc[mt][nt], 0, 0, 0);
    }
    if (has_next) {
      storeTiles(buf ^ 1, pa, pb);  // waits vmcnt here, after MFMA cover
      __syncthreads();
      buf ^= 1;
    }
  }
#pragma unroll
  for (int mt = 0; mt < 2; ++mt)
#pragma unroll
    for (int nt = 0; nt < 4; ++nt) {
      int f = n0 + wx * 64 + nt * 16 + lrow;
      float bias = b_dcn[f];
#pragma unroll
      for (int r = 0; r < 4; ++r) {
        int m = m0 + wy * 32 + mt * 16 + lq * 4 + r;
        float v = fmaxf(acc[mt][nt][r] + bias, 0.f);
        float fc = __builtin_nontemporal_load(&finecal[(size_t)m * 256 + f]);
        __builtin_nontemporal_store(v + fc, &outp[(size_t)m * 256 + f]);
      }
    }
}

// ---------------------------------------------------------------------------
extern "C" void kernel_launch(void* const* d_in, const int* in_sizes, int n_in,
                              void* d_out, int out_size, void* d_ws, size_t ws_size,
                              hipStream_t stream) {
  const float* coarse = (const float*)d_in[0];
  const float* fine   = (const float*)d_in[1];
  const float* w_att  = (const float*)d_in[2];
  const float* w_sel  = (const float*)d_in[3];
  const float* w_off  = (const float*)d_in[4];
  const float* w_om   = (const float*)d_in[5];
  const float* b_om   = (const float*)d_in[6];
  const float* w_dcn  = (const float*)d_in[7];
  const float* b_dcn  = (const float*)d_in[8];
  float* outp = (float*)d_out;

  char* base = (char*)d_ws;
  size_t o = 0;
  float* scale            = (float*)(base + o);          o += 4096;
  float* finecal          = (float*)(base + o);          o += 16777216;
  float* omb              = (float*)(base + o);          o += 14155776;
  unsigned short* upbf    = (unsigned short*)(base + o); o += 8388608;
  unsigned short* w_offT  = (unsigned short*)(base + o); o += 524288;
  unsigned short* w_omT   = (unsigned short*)(base + o); o += 2359296;  // 9*256*512
  unsigned short* w_selT  = (unsigned short*)(base + o); o += 131072;
  unsigned short* w_dcnT  = (unsigned short*)(base + o); o += 1179648;
  unsigned short* Sbuf    = (unsigned short*)(base + o);  // S region
  size_t fixed = o;
  // alignA/alignBf alias the S region (dead before S is written):
  unsigned short* alignA  = Sbuf;
  unsigned short* alignBf = (unsigned short*)((char*)Sbuf + 16777216);
  // partial pooling buffer aliases omb (dead until om_conv writes it)
  float* partial = omb;

  bool fullS = (ws_size >= fixed + 75497472);  // constant across calls

  prep_transpose<<<dim3(2048), dim3(256), 0, stream>>>(
      w_off, w_om, w_sel, w_dcn, w_offT, w_omT, w_selT, w_dcnT);
  pool_partial<<<dim3(64, 4), dim3(256), 0, stream>>>(fine, partial);
  pool_finish<<<dim3(4), dim3(256), 0, stream>>>(partial, w_att, scale);
  upsample_kernel<<<dim3(16384), dim3(256), 0, stream>>>(coarse, upbf, alignA);
  gemm_finecal_mfma<<<dim3(4, 128), dim3(256), 0, stream>>>(
      fine, scale, w_selT, finecal, alignA);
  gemm_align_mfma<<<dim3(8, 128), dim3(256), 0, stream>>>(alignA, w_offT, alignBf);
  om_conv_mfma<<<dim3(4, 128), dim3(256), 0, stream>>>(alignBf, w_omT, b_om, omb);

  if (fullS) {
    dcn_sample<<<dim3(512), dim3(256), 0, stream>>>(omb, upbf, Sbuf, 0);
    dcn_gemm<<<dim3(2, 256), dim3(256), 0, stream>>>(
        Sbuf, w_dcnT, b_dcn, finecal, outp, 0, KDC / 64);
  } else {
    // chunked: 2 batches (8192 rows of S) at a time; S region = 37.7 MB
    for (int ch = 0; ch < 2; ++ch) {
      dcn_sample<<<dim3(256), dim3(256), 0, stream>>>(omb, upbf, Sbuf, ch * 128);
      dcn_gemm<<<dim3(2, 128), dim3(256), 0, stream>>>(
          Sbuf, w_dcnT, b_dcn, finecal, outp, ch * 8192, KDC / 64);
    }
  }
}